// Round 4
// baseline (109.626 us; speedup 1.0000x reference)
//
#include <hip/hip_runtime.h>
#include <math.h>

#define NS   16383      // T-1 steps
#define NSP  16384      // padded stride for [dim][t] arrays
#define LPB  64         // timesteps per block (= lanes of a wave)
#define NBLK 256        // NS / LPB (ceil)
#define STR  65         // LDS row stride in floats

// ---- ws layout (floats) ----
#define OFF_ZT     0                         // 100*NSP
#define OFF_AT     (OFF_ZT + 100*NSP)        // 2*NSP
#define OFF_INTERT (OFF_AT + 2*NSP)          // 100*NSP
#define OFF_DELTAT (OFF_INTERT + 100*NSP)    // 50*NSP
#define OFF_W1T    (OFF_DELTAT + 50*NSP)     // 102*128
#define OFF_W2T    (OFF_W1T + 102*128)       // 100*128
#define OFF_W3T    (OFF_W2T + 100*128)       // 100*128
#define OFF_W4T    (OFF_W3T + 100*128)       // 100*64
#define OFF_W5T    (OFF_W4T + 100*64)        // 150*128
#define OFF_WZT    (OFF_W5T + 150*128)       // 100*128
#define OFF_CSUM   (OFF_WZT + 100*128)       // 50*NBLK
#define OFF_BZ     (OFF_CSUM + 50*NBLK)      // NBLK
#define OFF_BT     (OFF_BZ + NBLK)           // NBLK

__device__ __forceinline__ float lrelu(float x) { return fmaxf(x, 0.01f * x); }

// dense: 8 neuron slots per wave (16 waves), weights [K][128] as float4 (2/wave/k)
#define DENSE8(INLDS, KDIM, WT4, BIAS, acc)                                 \
    {                                                                       \
        _Pragma("unroll")                                                   \
        for (int j = 0; j < 8; ++j) {                                       \
            const int n = n0 + j;                                           \
            acc[j] = (n < 100) ? BIAS[n] : 0.f;                             \
        }                                                                   \
        _Pragma("unroll 8")                                                 \
        for (int k = 0; k < (KDIM); ++k) {                                  \
            const float r = INLDS[k * STR + lane];                          \
            const float4* Wk = (WT4) + k * 32 + w * 2;                      \
            _Pragma("unroll")                                               \
            for (int q = 0; q < 2; ++q) {                                   \
                const float4 wv = Wk[q];                                    \
                acc[4*q+0] = fmaf(r, wv.x, acc[4*q+0]);                     \
                acc[4*q+1] = fmaf(r, wv.y, acc[4*q+1]);                     \
                acc[4*q+2] = fmaf(r, wv.z, acc[4*q+2]);                     \
                acc[4*q+3] = fmaf(r, wv.w, acc[4*q+3]);                     \
            }                                                               \
        }                                                                   \
    }

// ---------- k0: fused z-transpose + weight prep ----------
__global__ __launch_bounds__(256)
void k0_prep(const float* __restrict__ z_seq, const float* __restrict__ a_seq,
             const float* __restrict__ W1, const float* __restrict__ W2,
             const float* __restrict__ W3, const float* __restrict__ W4,
             const float* __restrict__ W5, const float* __restrict__ Wz,
             float* __restrict__ ws)
{
    __shared__ float tile[50 * 65];
    const int bid = blockIdx.x;
    const int tid = threadIdx.x;

    if (bid < 512) {   // z transpose: [16384][100] -> zT [100][16384]
        const int tt = bid >> 1;
        const int cc = (bid & 1) * 50;
        for (int idx = tid; idx < 64 * 50; idx += 256) {
            const int l = idx / 50, j = idx - l * 50;
            tile[j * 65 + l] = z_seq[(tt * 64 + l) * 100 + cc + j];
        }
        __syncthreads();
        float* zT = ws + OFF_ZT;
        for (int idx = tid; idx < 50 * 64; idx += 256) {
            const int n = idx >> 6, l = idx & 63;
            zT[(cc + n) * NSP + tt * 64 + l] = tile[n * 65 + l];
        }
        return;
    }

    int idx = (bid - 512) * 256 + tid;
    if (idx < 102 * 128) {                       // W1T [102][128]
        const int k = idx >> 7, s = idx & 127;
        ws[OFF_W1T + idx] = (s < 100) ? W1[s * 102 + k] : 0.f;
        return;
    }
    idx -= 102 * 128;
    if (idx < 100 * 128) {                       // W2T
        const int k = idx >> 7, s = idx & 127;
        ws[OFF_W2T + idx] = (s < 100) ? W2[s * 100 + k] : 0.f;
        return;
    }
    idx -= 100 * 128;
    if (idx < 100 * 128) {                       // W3T
        const int k = idx >> 7, s = idx & 127;
        ws[OFF_W3T + idx] = (s < 100) ? W3[s * 100 + k] : 0.f;
        return;
    }
    idx -= 100 * 128;
    if (idx < 100 * 64) {                        // W4T [100][64]
        const int k = idx >> 6, s = idx & 63;
        ws[OFF_W4T + idx] = (s < 50) ? W4[s * 100 + k] : 0.f;
        return;
    }
    idx -= 100 * 64;
    if (idx < 150 * 128) {                       // W5T [150][128]
        const int k = idx >> 7, s = idx & 127;
        ws[OFF_W5T + idx] = (s < 100) ? W5[s * 150 + k] : 0.f;
        return;
    }
    idx -= 150 * 128;
    if (idx < 100 * 128) {                       // WZT
        const int k = idx >> 7, s = idx & 127;
        ws[OFF_WZT + idx] = (s < 100) ? Wz[s * 100 + k] : 0.f;
        return;
    }
    idx -= 100 * 128;
    if (idx < 2 * NSP) {                         // aT [2][NSP]
        const int j = idx >> 14, t = idx & (NSP - 1);
        ws[OFF_AT + idx] = (t < NS) ? a_seq[t * 2 + j] : 0.f;
        return;
    }
}

// ---------- k1: 4-layer encoder, 16 waves ----------
__global__ __launch_bounds__(1024)
void k1_encode(const float* __restrict__ ws_c, float* __restrict__ ws_m,
               const float* __restrict__ b1, const float* __restrict__ b2,
               const float* __restrict__ b3, const float* __restrict__ b4)
{
    __shared__ float A[102 * STR];

    const int tid  = threadIdx.x;
    const int lane = tid & 63;
    const int w    = __builtin_amdgcn_readfirstlane(tid >> 6);   // 0..15
    const int n0   = w * 8;
    const int blk  = blockIdx.x;
    const int t0   = blk * LPB;
    const bool vl  = (t0 + lane) < NS;

    const float*  zT   = ws_c + OFF_ZT;
    const float*  aT   = ws_c + OFF_AT;
    const float4* w1t4 = (const float4*)(ws_c + OFF_W1T);
    const float4* w2t4 = (const float4*)(ws_c + OFF_W2T);
    const float4* w3t4 = (const float4*)(ws_c + OFF_W3T);
    const float4* w4t4 = (const float4*)(ws_c + OFF_W4T);
    float* interT = ws_m + OFF_INTERT;
    float* deltaT = ws_m + OFF_DELTAT;
    float* csum   = ws_m + OFF_CSUM;

    // stage az: rows 0..1 = a, rows 2..101 = z
    for (int idx = tid; idx < 102 * 64; idx += 1024) {
        const int rr = idx >> 6, l = idx & 63;
        A[rr * STR + l] = (rr < 2) ? aT[rr * NSP + t0 + l] : zT[(rr - 2) * NSP + t0 + l];
    }
    __syncthreads();

    float acc[8];
    // L1: az(102) -> v1
    DENSE8(A, 102, w1t4, b1, acc);
    __syncthreads();
    #pragma unroll
    for (int j = 0; j < 8; ++j) {
        const int n = n0 + j;
        if (n < 100) A[n * STR + lane] = lrelu(acc[j]);
    }
    __syncthreads();

    // L2: v1 -> inter
    DENSE8(A, 100, w2t4, b2, acc);
    __syncthreads();
    #pragma unroll
    for (int j = 0; j < 8; ++j) {
        const int n = n0 + j;
        if (n < 100) {
            const float v = lrelu(acc[j]);
            A[n * STR + lane] = v;
            if (vl) interT[n * NSP + t0 + lane] = v;
        }
    }
    __syncthreads();

    // L3: inter -> u
    DENSE8(A, 100, w3t4, b3, acc);
    __syncthreads();
    #pragma unroll
    for (int j = 0; j < 8; ++j) {
        const int n = n0 + j;
        if (n < 100) A[n * STR + lane] = lrelu(acc[j]);
    }
    __syncthreads();

    // L4: delta = W4 @ u + b4, 4 slots/wave ([K][64])
    {
        float a4[4];
        #pragma unroll
        for (int j = 0; j < 4; ++j) {
            const int n = w * 4 + j;
            a4[j] = (n < 50) ? b4[n] : 0.f;
        }
        #pragma unroll 8
        for (int k = 0; k < 100; ++k) {
            const float r = A[k * STR + lane];
            const float4 wv = w4t4[k * 16 + w];
            a4[0] = fmaf(r, wv.x, a4[0]);
            a4[1] = fmaf(r, wv.y, a4[1]);
            a4[2] = fmaf(r, wv.z, a4[2]);
            a4[3] = fmaf(r, wv.w, a4[3]);
        }
        #pragma unroll
        for (int j = 0; j < 4; ++j) {
            const int n = w * 4 + j;
            if (n < 50) {
                const float d = vl ? a4[j] : 0.f;
                deltaT[n * NSP + t0 + lane] = d;
                float s = d;
                #pragma unroll
                for (int off = 32; off > 0; off >>= 1) s += __shfl_xor(s, off, 64);
                if (lane == 0) csum[n * NBLK + blk] = s;
            }
        }
    }
}

// ---------- k3: chunk-offset + h-scan + predict + losses (16 waves) ----------
__global__ __launch_bounds__(1024)
void k3_predict(const float* __restrict__ ws_c, float* __restrict__ ws_m,
                const float* __restrict__ term_seq,
                const float* __restrict__ b5, const float* __restrict__ bz,
                const float* __restrict__ Wt, const float* __restrict__ bt)
{
    __shared__ float X[100 * STR];   // inter -> i5
    __shared__ float H[50 * STR];    // delta -> h
    __shared__ float coff_s[50];
    __shared__ float red[16];

    const int tid  = threadIdx.x;
    const int lane = tid & 63;
    const int w    = __builtin_amdgcn_readfirstlane(tid >> 6);   // 0..15
    const int n0   = w * 8;
    const int blk  = blockIdx.x;
    const int t0   = blk * LPB;
    const bool vl  = (t0 + lane) < NS;

    const float*  zT     = ws_c + OFF_ZT;
    const float*  interT = ws_c + OFF_INTERT;
    const float*  deltaT = ws_c + OFF_DELTAT;
    const float*  csum   = ws_c + OFF_CSUM;
    const float4* w5t4   = (const float4*)(ws_c + OFF_W5T);
    const float4* wzt4   = (const float4*)(ws_c + OFF_WZT);
    float* g_bz = ws_m + OFF_BZ;
    float* g_bt = ws_m + OFF_BT;

    for (int idx = tid; idx < 100 * 64; idx += 1024) {
        const int n = idx >> 6, l = idx & 63;
        X[n * STR + l] = (t0 + l < NS) ? interT[n * NSP + t0 + l] : 0.f;
    }
    for (int idx = tid; idx < 50 * 64; idx += 1024) {
        const int n = idx >> 6, l = idx & 63;
        H[n * STR + l] = deltaT[n * NSP + t0 + l];
    }

    // chunk offsets: sum csum[n][0..blk) cooperatively (lanes split chunks)
    for (int n = w; n < 50; n += 16) {
        float s = 0.f;
        #pragma unroll
        for (int i = 0; i < 4; ++i) {
            const int c = lane + 64 * i;
            if (c < blk) s += csum[n * NBLK + c];
        }
        #pragma unroll
        for (int off = 32; off > 0; off >>= 1) s += __shfl_xor(s, off, 64);
        if (lane == 0) coff_s[n] = s;
    }
    __syncthreads();

    // inclusive scan over 64 lanes per h-dim + chunk offset
    for (int n = w; n < 50; n += 16) {
        float v = H[n * STR + lane];
        #pragma unroll
        for (int off = 1; off < 64; off <<= 1) {
            const float u = __shfl_up(v, off, 64);
            if (lane >= off) v += u;
        }
        H[n * STR + lane] = v + coff_s[n];
    }
    __syncthreads();

    // L5: i5 = lrelu(W5 @ [h(50); inter(100)] + b5)
    float acc[8];
    #pragma unroll
    for (int j = 0; j < 8; ++j) {
        const int n = n0 + j;
        acc[j] = (n < 100) ? b5[n] : 0.f;
    }
    #pragma unroll 8
    for (int k = 0; k < 50; ++k) {
        const float r = H[k * STR + lane];
        const float4* Wk = w5t4 + k * 32 + w * 2;
        #pragma unroll
        for (int q = 0; q < 2; ++q) {
            const float4 wv = Wk[q];
            acc[4*q+0] = fmaf(r, wv.x, acc[4*q+0]);
            acc[4*q+1] = fmaf(r, wv.y, acc[4*q+1]);
            acc[4*q+2] = fmaf(r, wv.z, acc[4*q+2]);
            acc[4*q+3] = fmaf(r, wv.w, acc[4*q+3]);
        }
    }
    #pragma unroll 8
    for (int k = 0; k < 100; ++k) {
        const float r = X[k * STR + lane];
        const float4* Wk = w5t4 + (50 + k) * 32 + w * 2;
        #pragma unroll
        for (int q = 0; q < 2; ++q) {
            const float4 wv = Wk[q];
            acc[4*q+0] = fmaf(r, wv.x, acc[4*q+0]);
            acc[4*q+1] = fmaf(r, wv.y, acc[4*q+1]);
            acc[4*q+2] = fmaf(r, wv.z, acc[4*q+2]);
            acc[4*q+3] = fmaf(r, wv.w, acc[4*q+3]);
        }
    }
    __syncthreads();
    #pragma unroll
    for (int j = 0; j < 8; ++j) {
        const int n = n0 + j;
        if (n < 100) X[n * STR + lane] = lrelu(acc[j]);
    }
    __syncthreads();

    // prefetch z_next (hidden under Wz dense loop)
    float zn[8];
    {
        const int t1 = min(t0 + lane + 1, NS);
        #pragma unroll
        for (int j = 0; j < 8; ++j) {
            const int n = n0 + j;
            zn[j] = (n < 100) ? zT[n * NSP + t1] : 0.f;
        }
    }

    // z_pred = Wz @ i5 + bz; squared error
    float zpart = 0.f;
    {
        float a2[8];
        #pragma unroll
        for (int j = 0; j < 8; ++j) {
            const int n = n0 + j;
            a2[j] = (n < 100) ? bz[n] : 0.f;
        }
        #pragma unroll 8
        for (int k = 0; k < 100; ++k) {
            const float r = X[k * STR + lane];
            const float4* Wk = wzt4 + k * 32 + w * 2;
            #pragma unroll
            for (int q = 0; q < 2; ++q) {
                const float4 wv = Wk[q];
                a2[4*q+0] = fmaf(r, wv.x, a2[4*q+0]);
                a2[4*q+1] = fmaf(r, wv.y, a2[4*q+1]);
                a2[4*q+2] = fmaf(r, wv.z, a2[4*q+2]);
                a2[4*q+3] = fmaf(r, wv.w, a2[4*q+3]);
            }
        }
        #pragma unroll
        for (int j = 0; j < 8; ++j) {
            const int n = n0 + j;
            if (n < 100) {
                const float d = zn[j] - a2[j];
                zpart += d * d;
            }
        }
        if (!vl) zpart = 0.f;
    }

    // t_logit + BCE (wave 0)
    float tpart = 0.f;
    if (w == 0) {
        float a = bt[0];
        #pragma unroll 4
        for (int k = 0; k < 100; ++k) a = fmaf(X[k * STR + lane], Wt[k], a);
        if (vl) {
            const float y = term_seq[t0 + lane + 1];
            tpart = fmaxf(a, 0.f) - a * y + log1pf(expf(-fabsf(a)));
        }
    }

    #pragma unroll
    for (int off = 32; off > 0; off >>= 1) zpart += __shfl_xor(zpart, off, 64);
    if (lane == 0) red[w] = zpart;
    __syncthreads();
    if (tid == 0) {
        float s = 0.f;
        #pragma unroll
        for (int i = 0; i < 16; ++i) s += red[i];
        g_bz[blk] = s;
    }
    if (w == 0) {
        #pragma unroll
        for (int off = 32; off > 0; off >>= 1) tpart += __shfl_xor(tpart, off, 64);
        if (lane == 0) g_bt[blk] = tpart;
    }
}

// ---------- k4: final reduce ----------
__global__ __launch_bounds__(256)
void k4_final(const float* __restrict__ ws_c, float* __restrict__ out)
{
    __shared__ float rz[4], rt[4];
    const float* g_bz = ws_c + OFF_BZ;
    const float* g_bt = ws_c + OFF_BT;
    const int tid  = threadIdx.x;
    const int lane = tid & 63;
    const int w    = tid >> 6;
    float z = g_bz[tid];
    float t = g_bt[tid];
    #pragma unroll
    for (int off = 32; off > 0; off >>= 1) {
        z += __shfl_xor(z, off, 64);
        t += __shfl_xor(t, off, 64);
    }
    if (lane == 0) { rz[w] = z; rt[w] = t; }
    __syncthreads();
    if (tid == 0) {
        const float sz = rz[0] + rz[1] + rz[2] + rz[3];
        const float st = rt[0] + rt[1] + rt[2] + rt[3];
        const float zl = sz / (100.0f * NS);
        const float tl = st / NS;
        out[0] = zl + tl;
        out[1] = zl;
        out[2] = tl;
    }
}

extern "C" void kernel_launch(void* const* d_in, const int* in_sizes, int n_in,
                              void* d_out, int out_size, void* d_ws, size_t ws_size,
                              hipStream_t stream)
{
    const float* z_seq = (const float*)d_in[0];
    const float* a_seq = (const float*)d_in[1];
    const float* term  = (const float*)d_in[2];
    const float* W1 = (const float*)d_in[3];  const float* b1 = (const float*)d_in[4];
    const float* W2 = (const float*)d_in[5];  const float* b2 = (const float*)d_in[6];
    const float* W3 = (const float*)d_in[7];  const float* b3 = (const float*)d_in[8];
    const float* W4 = (const float*)d_in[9];  const float* b4 = (const float*)d_in[10];
    const float* W5 = (const float*)d_in[11]; const float* b5 = (const float*)d_in[12];
    const float* Wz = (const float*)d_in[13]; const float* bz = (const float*)d_in[14];
    const float* Wt = (const float*)d_in[15]; const float* bt = (const float*)d_in[16];
    float* out = (float*)d_out;
    float* ws  = (float*)d_ws;

    k0_prep<<<941, 256, 0, stream>>>(z_seq, a_seq, W1, W2, W3, W4, W5, Wz, ws);
    k1_encode<<<NBLK, 1024, 0, stream>>>(ws, ws, b1, b2, b3, b4);
    k3_predict<<<NBLK, 1024, 0, stream>>>(ws, ws, term, b5, bz, Wt, bt);
    k4_final<<<1, 256, 0, stream>>>(ws, out);
}

// Round 5
// 107.382 us; speedup vs baseline: 1.0209x; 1.0209x over previous
//
#include <hip/hip_runtime.h>
#include <math.h>

#define NS   16383      // T-1 steps
#define NSP  16384      // stride for [dim][t] arrays
#define LPB  64         // timesteps per block (= lanes)
#define NBLK 256        // NS / LPB
#define TPB  512        // 8 waves

// ---- ws layout (floats) ----
#define OFF_INTERT 0                          // 100*NSP
#define OFF_DELTAT (OFF_INTERT + 100*NSP)     // 50*NSP
#define OFF_W1T    (OFF_DELTAT + 50*NSP)      // 104*128
#define OFF_W2T    (OFF_W1T + 104*128)        // 100*128
#define OFF_W3T    (OFF_W2T + 100*128)        // 100*128
#define OFF_W4T    (OFF_W3T + 100*128)        // 100*64
#define OFF_W5T    (OFF_W4T + 100*64)         // 152*128
#define OFF_WZT    (OFF_W5T + 152*128)        // 100*128
#define OFF_CSUM   (OFF_WZT + 100*128)        // 50*NBLK
#define OFF_BZ     (OFF_CSUM + 50*NBLK)       // NBLK
#define OFF_BT     (OFF_BZ + NBLK)            // NBLK

__device__ __forceinline__ float lrelu(float x) { return fmaxf(x, 0.01f * x); }

// swizzled LDS row addressing: row l (stride 128 floats), granule g (4 floats)
// physical granule = g ^ (l&7)  -> conflict-free b128 row reads & column writes
__device__ __forceinline__ int swz4(int l, int g) { return (l << 7) + ((g ^ (l & 7)) << 2); }
__device__ __forceinline__ int swz1(int l, int e) { return (l << 7) + ((((e >> 2) ^ (l & 7)) << 2) | (e & 3)); }

#define BIAS16(B)                                                          \
    _Pragma("unroll")                                                      \
    for (int j = 0; j < 16; ++j) {                                         \
        const int n = n0 + j;                                              \
        acc[j] = (n < 100) ? (B)[n] : 0.f;                                 \
    }

#define ACC16(BUF, GN, W)                                                  \
    _Pragma("unroll 4")                                                    \
    for (int g = 0; g < (GN); ++g) {                                       \
        const float4 t = *(const float4*)&(BUF)[swz4(lane, g)];            \
        const float rr[4] = {t.x, t.y, t.z, t.w};                          \
        _Pragma("unroll")                                                  \
        for (int c = 0; c < 4; ++c) {                                      \
            const float* Wr = (W) + (g * 4 + c) * 128 + n0;                \
            _Pragma("unroll")                                              \
            for (int j = 0; j < 16; ++j)                                   \
                acc[j] = fmaf(rr[c], Wr[j], acc[j]);                       \
        }                                                                  \
    }

#define LRELU16                                                            \
    _Pragma("unroll")                                                      \
    for (int j = 0; j < 16; ++j) acc[j] = lrelu(acc[j]);

#define WRITE16(BUF)                                                       \
    _Pragma("unroll")                                                      \
    for (int q = 0; q < 4; ++q) {                                          \
        float4 v;                                                          \
        v.x = acc[q*4+0]; v.y = acc[q*4+1]; v.z = acc[q*4+2]; v.w = acc[q*4+3]; \
        *(float4*)&(BUF)[swz4(lane, w * 4 + q)] = v;                       \
    }

// ---------- k0: weight transposes only ----------
__global__ __launch_bounds__(256)
void k0_prep(const float* __restrict__ W1, const float* __restrict__ W2,
             const float* __restrict__ W3, const float* __restrict__ W4,
             const float* __restrict__ W5, const float* __restrict__ Wz,
             float* __restrict__ ws)
{
    int idx = blockIdx.x * 256 + threadIdx.x;
    if (idx < 104 * 128) {                       // W1T [104][128]
        const int k = idx >> 7, s = idx & 127;
        ws[OFF_W1T + idx] = (k < 102 && s < 100) ? W1[s * 102 + k] : 0.f;
        return;
    }
    idx -= 104 * 128;
    if (idx < 100 * 128) {                       // W2T [100][128]
        const int k = idx >> 7, s = idx & 127;
        ws[OFF_W2T + idx] = (s < 100) ? W2[s * 100 + k] : 0.f;
        return;
    }
    idx -= 100 * 128;
    if (idx < 100 * 128) {                       // W3T
        const int k = idx >> 7, s = idx & 127;
        ws[OFF_W3T + idx] = (s < 100) ? W3[s * 100 + k] : 0.f;
        return;
    }
    idx -= 100 * 128;
    if (idx < 100 * 64) {                        // W4T [100][64]
        const int k = idx >> 6, s = idx & 63;
        ws[OFF_W4T + idx] = (s < 50) ? W4[s * 100 + k] : 0.f;
        return;
    }
    idx -= 100 * 64;
    if (idx < 152 * 128) {                       // W5T [152][128]
        const int k = idx >> 7, s = idx & 127;
        ws[OFF_W5T + idx] = (k < 150 && s < 100) ? W5[s * 150 + k] : 0.f;
        return;
    }
    idx -= 152 * 128;
    if (idx < 100 * 128) {                       // WzT
        const int k = idx >> 7, s = idx & 127;
        ws[OFF_WZT + idx] = (s < 100) ? Wz[s * 100 + k] : 0.f;
        return;
    }
}

// ---------- k1: 4-layer encoder ----------
__global__ __launch_bounds__(TPB)
void k1_encode(const float* __restrict__ z_seq, const float* __restrict__ a_seq,
               const float* ws_c, float* ws_m,
               const float* __restrict__ b1, const float* __restrict__ b2,
               const float* __restrict__ b3, const float* __restrict__ b4)
{
    __shared__ float Vp[64 * 128];
    __shared__ float Vq[64 * 128];

    const int tid  = threadIdx.x;
    const int lane = tid & 63;
    const int w    = __builtin_amdgcn_readfirstlane(tid >> 6);   // 0..7
    const int n0   = w * 16;
    const int blk  = blockIdx.x;
    const int t0   = blk * LPB;
    const bool vl  = (t0 + lane) < NS;

    const float* w1t = ws_c + OFF_W1T;
    const float* w2t = ws_c + OFF_W2T;
    const float* w3t = ws_c + OFF_W3T;
    const float* w4t = ws_c + OFF_W4T;
    float* interT = ws_m + OFF_INTERT;
    float* deltaT = ws_m + OFF_DELTAT;
    float* csum   = ws_m + OFF_CSUM;

    // stage az rows: e=0,1 <- a ; e=2..101 <- z ; e=102,103 <- 0   (coalesced)
    for (int i = tid; i < 6400; i += TPB) {
        const int l = i / 100, n = i - l * 100;
        Vp[swz1(l, n + 2)] = z_seq[(t0 + l) * 100 + n];
    }
    if (tid < 128) {
        const int l = tid >> 1, e = tid & 1;
        Vp[swz1(l, e)] = a_seq[(t0 + l) * 2 + e];
    } else if (tid < 256) {
        const int tt = tid - 128;
        const int l = tt >> 1, e = 102 + (tt & 1);
        Vp[swz1(l, e)] = 0.f;
    }
    __syncthreads();

    float acc[16];

    // L1: az(104 padded) -> v1
    BIAS16(b1);
    ACC16(Vp, 26, w1t);
    LRELU16;
    WRITE16(Vq);
    __syncthreads();

    // L2: v1 -> inter (also store to global, coalesced per slot)
    BIAS16(b2);
    ACC16(Vq, 25, w2t);
    LRELU16;
    WRITE16(Vp);
    #pragma unroll
    for (int j = 0; j < 16; ++j) {
        const int n = n0 + j;
        if (n < 100) interT[n * NSP + t0 + lane] = acc[j];
    }
    __syncthreads();

    // L3: inter -> u
    BIAS16(b3);
    ACC16(Vp, 25, w3t);
    LRELU16;
    WRITE16(Vq);
    __syncthreads();

    // L4: delta = W4 @ u + b4 (8 slots/wave, [k][64] weights)
    {
        const int m0 = w * 8;
        float a2[8];
        #pragma unroll
        for (int j = 0; j < 8; ++j) {
            const int n = m0 + j;
            a2[j] = (n < 50) ? b4[n] : 0.f;
        }
        #pragma unroll 4
        for (int g = 0; g < 25; ++g) {
            const float4 t = *(const float4*)&Vq[swz4(lane, g)];
            const float rr[4] = {t.x, t.y, t.z, t.w};
            #pragma unroll
            for (int c = 0; c < 4; ++c) {
                const float* Wr = w4t + (g * 4 + c) * 64 + m0;
                #pragma unroll
                for (int j = 0; j < 8; ++j)
                    a2[j] = fmaf(rr[c], Wr[j], a2[j]);
            }
        }
        #pragma unroll
        for (int j = 0; j < 8; ++j) {
            const int n = m0 + j;
            if (n < 50) {
                const float d = vl ? a2[j] : 0.f;
                deltaT[n * NSP + t0 + lane] = d;
                float s = d;
                #pragma unroll
                for (int off = 32; off > 0; off >>= 1) s += __shfl_xor(s, off, 64);
                if (lane == 0) csum[n * NBLK + blk] = s;
            }
        }
    }
}

// ---------- k3: coff + h-scan + predict + losses ----------
__global__ __launch_bounds__(TPB)
void k3_predict(const float* __restrict__ z_seq, const float* __restrict__ term_seq,
                const float* ws_c, float* ws_m,
                const float* __restrict__ b5, const float* __restrict__ bz,
                const float* __restrict__ Wt, const float* __restrict__ bt)
{
    __shared__ float Vi[64 * 128];   // inter rows
    __shared__ float Vh[64 * 128];   // delta -> h rows
    __shared__ float Vz[64 * 128];   // z_next rows
    __shared__ float V5[64 * 128];   // i5 rows
    __shared__ float coff_s[50];
    __shared__ float red[8];

    const int tid  = threadIdx.x;
    const int lane = tid & 63;
    const int w    = __builtin_amdgcn_readfirstlane(tid >> 6);
    const int n0   = w * 16;
    const int blk  = blockIdx.x;
    const int t0   = blk * LPB;
    const bool vl  = (t0 + lane) < NS;

    const float* interT = ws_c + OFF_INTERT;
    const float* deltaT = ws_c + OFF_DELTAT;
    const float* csum   = ws_c + OFF_CSUM;
    const float* w5t    = ws_c + OFF_W5T;
    const float* wzt    = ws_c + OFF_WZT;
    float* g_bz = ws_m + OFF_BZ;
    float* g_bt = ws_m + OFF_BT;

    // stage inter / delta ([n][t] coalesced) and z_next (contiguous rows)
    for (int i = tid; i < 6400; i += TPB) {
        const int n = i >> 6, l = i & 63;
        Vi[swz1(l, n)] = interT[n * NSP + t0 + l];
    }
    for (int i = tid; i < 3200; i += TPB) {
        const int n = i >> 6, l = i & 63;
        Vh[swz1(l, n)] = deltaT[n * NSP + t0 + l];
    }
    if (tid < 128) {
        const int l = tid >> 1, e = 50 + (tid & 1);
        Vh[swz1(l, e)] = 0.f;
    }
    for (int i = tid; i < 6400; i += TPB) {
        const int l = i / 100, n = i - l * 100;
        int t1 = t0 + l + 1; t1 = t1 > NS ? NS : t1;
        Vz[swz1(l, n)] = z_seq[t1 * 100 + n];
    }

    // chunk offsets (global reads; same-wave produce/consume, no barrier needed)
    for (int n = w; n < 50; n += 8) {
        float s = 0.f;
        #pragma unroll
        for (int i2 = 0; i2 < 4; ++i2) {
            const int c = lane + (i2 << 6);
            if (c < blk) s += csum[n * NBLK + c];
        }
        #pragma unroll
        for (int off = 32; off > 0; off >>= 1) s += __shfl_xor(s, off, 64);
        if (lane == 0) coff_s[n] = s;
    }
    __syncthreads();

    // inclusive scan over lanes per h-dim, + chunk offset (in place in Vh)
    for (int n = w; n < 50; n += 8) {
        float v = Vh[swz1(lane, n)];
        #pragma unroll
        for (int off = 1; off < 64; off <<= 1) {
            const float u = __shfl_up(v, off, 64);
            if (lane >= off) v += u;
        }
        Vh[swz1(lane, n)] = v + coff_s[n];
    }
    __syncthreads();

    float acc[16];

    // L5: i5 = lrelu(W5 @ [h(50); inter(100)] + b5) — two accumulation passes
    BIAS16(b5);
    ACC16(Vh, 13, w5t);               // h part: rows 0..51 (50,51 hit zero pads)
    ACC16(Vi, 25, w5t + 50 * 128);    // inter part: rows 50..149
    LRELU16;
    WRITE16(V5);
    __syncthreads();

    // z_pred = Wz @ i5 + bz ; squared error vs z_next
    BIAS16(bz);
    ACC16(V5, 25, wzt);
    float zpart = 0.f;
    #pragma unroll
    for (int q = 0; q < 4; ++q) {
        const int n = n0 + q * 4;
        if (n + 3 < 100) {
            const float4 zn4 = *(const float4*)&Vz[swz4(lane, w * 4 + q)];
            float d;
            d = zn4.x - acc[q*4+0]; zpart += d * d;
            d = zn4.y - acc[q*4+1]; zpart += d * d;
            d = zn4.z - acc[q*4+2]; zpart += d * d;
            d = zn4.w - acc[q*4+3]; zpart += d * d;
        }
    }
    if (!vl) zpart = 0.f;

    // t_logit + BCE (wave 0)
    float tpart = 0.f;
    if (w == 0) {
        float a = bt[0];
        #pragma unroll 4
        for (int g = 0; g < 25; ++g) {
            const float4 t = *(const float4*)&V5[swz4(lane, g)];
            a = fmaf(t.x, Wt[g*4+0], a);
            a = fmaf(t.y, Wt[g*4+1], a);
            a = fmaf(t.z, Wt[g*4+2], a);
            a = fmaf(t.w, Wt[g*4+3], a);
        }
        if (vl) {
            const float y = term_seq[t0 + lane + 1];
            tpart = fmaxf(a, 0.f) - a * y + log1pf(expf(-fabsf(a)));
        }
    }

    #pragma unroll
    for (int off = 32; off > 0; off >>= 1) zpart += __shfl_xor(zpart, off, 64);
    if (lane == 0) red[w] = zpart;
    __syncthreads();
    if (tid == 0) {
        float s = 0.f;
        #pragma unroll
        for (int i = 0; i < 8; ++i) s += red[i];
        g_bz[blk] = s;
    }
    if (w == 0) {
        #pragma unroll
        for (int off = 32; off > 0; off >>= 1) tpart += __shfl_xor(tpart, off, 64);
        if (lane == 0) g_bt[blk] = tpart;
    }
}

// ---------- k4: final reduce ----------
__global__ __launch_bounds__(256)
void k4_final(const float* ws_c, float* __restrict__ out)
{
    __shared__ float rz[4], rt[4];
    const float* g_bz = ws_c + OFF_BZ;
    const float* g_bt = ws_c + OFF_BT;
    const int tid  = threadIdx.x;
    const int lane = tid & 63;
    const int w    = tid >> 6;
    float z = g_bz[tid];
    float t = g_bt[tid];
    #pragma unroll
    for (int off = 32; off > 0; off >>= 1) {
        z += __shfl_xor(z, off, 64);
        t += __shfl_xor(t, off, 64);
    }
    if (lane == 0) { rz[w] = z; rt[w] = t; }
    __syncthreads();
    if (tid == 0) {
        const float sz = rz[0] + rz[1] + rz[2] + rz[3];
        const float st = rt[0] + rt[1] + rt[2] + rt[3];
        const float zl = sz / (100.0f * NS);
        const float tl = st / NS;
        out[0] = zl + tl;
        out[1] = zl;
        out[2] = tl;
    }
}

extern "C" void kernel_launch(void* const* d_in, const int* in_sizes, int n_in,
                              void* d_out, int out_size, void* d_ws, size_t ws_size,
                              hipStream_t stream)
{
    const float* z_seq = (const float*)d_in[0];
    const float* a_seq = (const float*)d_in[1];
    const float* term  = (const float*)d_in[2];
    const float* W1 = (const float*)d_in[3];  const float* b1 = (const float*)d_in[4];
    const float* W2 = (const float*)d_in[5];  const float* b2 = (const float*)d_in[6];
    const float* W3 = (const float*)d_in[7];  const float* b3 = (const float*)d_in[8];
    const float* W4 = (const float*)d_in[9];  const float* b4 = (const float*)d_in[10];
    const float* W5 = (const float*)d_in[11]; const float* b5 = (const float*)d_in[12];
    const float* Wz = (const float*)d_in[13]; const float* bz = (const float*)d_in[14];
    const float* Wt = (const float*)d_in[15]; const float* bt = (const float*)d_in[16];
    float* out = (float*)d_out;
    float* ws  = (float*)d_ws;

    k0_prep<<<303, 256, 0, stream>>>(W1, W2, W3, W4, W5, Wz, ws);
    k1_encode<<<NBLK, TPB, 0, stream>>>(z_seq, a_seq, ws, ws, b1, b2, b3, b4);
    k3_predict<<<NBLK, TPB, 0, stream>>>(z_seq, term, ws, ws, b5, bz, Wt, bt);
    k4_final<<<1, 256, 0, stream>>>(ws, out);
}

// Round 6
// 40.681 us; speedup vs baseline: 2.6948x; 2.6396x over previous
//
#include <hip/hip_runtime.h>
#include <math.h>

#define NS   16383
#define NSP  16384
#define NBLK 256

// ---- ws layout (float units) ----
#define OFF_INTR 0                          // interR [16384][64] uint (2xbf16) = 1048576 floats
#define OFF_DELT (OFF_INTR + 1048576)       // deltaT [50][NSP] f32 = 819200
#define OFF_CSUM (OFF_DELT + 819200)        // 50*NBLK
#define OFF_BZ   (OFF_CSUM + 12800)         // NBLK
#define OFF_BT   (OFF_BZ + 256)             // NBLK
#define OFF_PACK (OFF_BT + 256)             // 98304 ushort = 49152 floats

// ---- weight-pack offsets (ushort units) ----
#define PK1 0          // L1: NT=8 KS=4
#define PK2 16384      // L2: NT=8 KS=4
#define PK3 32768      // L3: NT=8 KS=4
#define PK4 49152      // L4: NT=4 KS=4
#define PK5 57344      // L5: NT=8 KS=6
#define PKZ 81920      // Lz: NT=8 KS=4
#define PKTOT 98304

using bf16x8 = __attribute__((ext_vector_type(8))) short;
using f32x4  = __attribute__((ext_vector_type(4))) float;

__device__ __forceinline__ unsigned short f2bf(float f) {
    unsigned int x = __float_as_uint(f);
    return (unsigned short)((x + 0x7fffu + ((x >> 16) & 1u)) >> 16);
}
__device__ __forceinline__ float bf2f(unsigned short u) {
    return __uint_as_float(((unsigned int)u) << 16);
}
__device__ __forceinline__ float lrelu(float x) { return fmaxf(x, 0.01f * x); }

// A-fragment: row = mt*16 + (lane&15), k = kc + 8*(lane>>4) .. +7 (contiguous b128)
// LDS rows bf16, XOR-swizzled: short-idx ^= (row&7)<<3  (16B granule spread)
__device__ __forceinline__ bf16x8 ldA(const unsigned short* buf, int strideSh, int row, int kc) {
    const int idx = (row * strideSh + kc) ^ ((row & 7) << 3);
    return *(const bf16x8*)(buf + idx);
}
// B-fragment: pre-packed lane-linear in global (coalesced dwordx4)
__device__ __forceinline__ bf16x8 ldB(const unsigned short* pk, int KS, int nt, int ks, int lane) {
    return *(const bf16x8*)(pk + (size_t)(((nt * KS + ks) << 6) + lane) * 8);
}
__device__ __forceinline__ f32x4 MF(bf16x8 a, bf16x8 b, f32x4 c) {
    return __builtin_amdgcn_mfma_f32_16x16x32_bf16(a, b, c, 0, 0, 0);
}

// ---------- k0: pack weights into MFMA B-fragment order (bf16) ----------
__global__ __launch_bounds__(256)
void k0_pack(const float* __restrict__ W1, const float* __restrict__ W2,
             const float* __restrict__ W3, const float* __restrict__ W4,
             const float* __restrict__ W5, const float* __restrict__ Wz,
             float* __restrict__ ws)
{
    const int idx = blockIdx.x * 256 + threadIdx.x;
    if (idx >= PKTOT) return;
    int e, KS, layer;
    if      (idx < PK2) { layer = 1; e = idx - PK1; KS = 4; }
    else if (idx < PK3) { layer = 2; e = idx - PK2; KS = 4; }
    else if (idx < PK4) { layer = 3; e = idx - PK3; KS = 4; }
    else if (idx < PK5) { layer = 4; e = idx - PK4; KS = 4; }
    else if (idx < PKZ) { layer = 5; e = idx - PK5; KS = 6; }
    else                { layer = 6; e = idx - PKZ; KS = 4; }
    const int j    = e & 7;
    const int ln   = (e >> 3) & 63;
    const int rest = e >> 9;
    const int ks   = rest % KS;
    const int nt   = rest / KS;
    const int n    = nt * 16 + (ln & 15);
    const int k    = ks * 32 + ((ln >> 4) << 3) + j;
    float v = 0.f;
    if (layer == 1)      { if (n < 100 && k < 102) v = W1[n * 102 + k]; }          // k: 0,1=a 2..101=z
    else if (layer == 2) { if (n < 100 && k < 100) v = W2[n * 100 + k]; }
    else if (layer == 3) { if (n < 100 && k < 100) v = W3[n * 100 + k]; }
    else if (layer == 4) { if (n < 50  && k < 100) v = W4[n * 100 + k]; }
    else if (layer == 5) { if (n < 100) {                                           // k: 0..49=h, 64..163=inter
                               if (k < 50) v = W5[n * 150 + k];
                               else if (k >= 64 && k < 164) v = W5[n * 150 + k - 14]; } }
    else                 { if (n < 100 && k < 100) v = Wz[n * 100 + k]; }
    ((unsigned short*)(ws + OFF_PACK))[idx] = f2bf(v);
}

// 16x16 output-tile layer: IN lds rows (stride 128 sh) -> OUT lds rows (stride 128 sh)
#define MFMA_LAYER8(INBUF, PKOFF, BIAS, OUTBUF)                                     \
    {                                                                               \
        f32x4 acc[4];                                                               \
        _Pragma("unroll")                                                           \
        for (int q = 0; q < 4; ++q) {                                               \
            const int n = (ntb + q) * 16 + rl;                                      \
            const float bv = (n < 100) ? (BIAS)[n] : 0.f;                           \
            f32x4 av; av.x = bv; av.y = bv; av.z = bv; av.w = bv;                   \
            acc[q] = av;                                                            \
        }                                                                           \
        bf16x8 bfr[16];                                                             \
        _Pragma("unroll")                                                           \
        for (int ks = 0; ks < 4; ++ks) {                                            \
            _Pragma("unroll")                                                       \
            for (int q = 0; q < 4; ++q)                                             \
                bfr[ks * 4 + q] = ldB(pack + (PKOFF), 4, ntb + q, ks, lane);        \
        }                                                                           \
        _Pragma("unroll")                                                           \
        for (int ks = 0; ks < 4; ++ks) {                                            \
            const bf16x8 a = ldA(INBUF, 128, mt * 16 + rl, ks * 32 + g8);           \
            _Pragma("unroll")                                                       \
            for (int q = 0; q < 4; ++q) acc[q] = MF(a, bfr[ks * 4 + q], acc[q]);    \
        }                                                                           \
        _Pragma("unroll")                                                           \
        for (int q = 0; q < 4; ++q) {                                               \
            const int col = (ntb + q) * 16 + rl;                                    \
            _Pragma("unroll")                                                       \
            for (int r = 0; r < 4; ++r) {                                           \
                const int row = mt * 16 + dr + r;                                   \
                const float v = lrelu(acc[q][r]);                                   \
                (OUTBUF)[((row << 7) + col) ^ ((row & 7) << 3)] = f2bf(v);          \
            }                                                                       \
        }                                                                           \
    }

// ---------- k1: L1..L4 via MFMA ----------
__global__ __launch_bounds__(512)
void k1_encode(const float* __restrict__ z_seq, const float* __restrict__ a_seq,
               const float* __restrict__ b1, const float* __restrict__ b2,
               const float* __restrict__ b3, const float* __restrict__ b4,
               float* __restrict__ ws)
{
    __shared__ unsigned short Vp[64 * 128];
    __shared__ unsigned short Vq[64 * 128];
    __shared__ float Dl[64 * 64];

    const int tid  = threadIdx.x;
    const int lane = tid & 63;
    const int w    = __builtin_amdgcn_readfirstlane(tid >> 6);
    const int blk  = blockIdx.x;
    const int t0   = blk * 64;

    const unsigned short* pack = (const unsigned short*)(ws + OFF_PACK);
    unsigned int* interR = (unsigned int*)(ws + OFF_INTR);
    float* deltaT = ws + OFF_DELT;
    float* csum   = ws + OFF_CSUM;

    // stage az rows bf16: cols 0,1=a; 2..101=z; 102..127=0
    if (tid < 64) {
        const int t = tid;
        const float a0 = a_seq[(t0 + t) * 2 + 0];
        const float a1 = a_seq[(t0 + t) * 2 + 1];
        *(unsigned int*)&Vp[((t << 7) + 0) ^ ((t & 7) << 3)] =
            (unsigned int)f2bf(a0) | ((unsigned int)f2bf(a1) << 16);
    }
    for (int i = tid; i < 3200; i += 512) {
        const int t = i / 50, p = i - t * 50;
        const float2 z2 = *(const float2*)(z_seq + (size_t)(t0 + t) * 100 + 2 * p);
        *(unsigned int*)&Vp[((t << 7) + 2 + 2 * p) ^ ((t & 7) << 3)] =
            (unsigned int)f2bf(z2.x) | ((unsigned int)f2bf(z2.y) << 16);
    }
    for (int i = tid; i < 832; i += 512) {
        const int t = i / 13, p = i - t * 13;
        *(unsigned int*)&Vp[((t << 7) + 102 + 2 * p) ^ ((t & 7) << 3)] = 0u;
    }
    __syncthreads();

    const int mt  = w >> 1;
    const int ntb = (w & 1) * 4;
    const int rl  = lane & 15;
    const int g8  = (lane >> 4) << 3;
    const int dr  = (lane >> 4) << 2;

    MFMA_LAYER8(Vp, PK1, b1, Vq);      // L1: az -> v1
    __syncthreads();
    MFMA_LAYER8(Vq, PK2, b2, Vp);      // L2: v1 -> inter
    __syncthreads();

    // copy inter rows (bf16 pairs) to global; L3 in same phase (both read Vp)
    for (int i = tid; i < 4096; i += 512) {
        const int t = i >> 6, c2 = i & 63;
        interR[(size_t)(t0 + t) * 64 + c2] =
            *(const unsigned int*)&Vp[((t << 7) + (c2 << 1)) ^ ((t & 7) << 3)];
    }
    MFMA_LAYER8(Vp, PK3, b3, Vq);      // L3: inter -> u
    __syncthreads();

    // L4: delta = W4 @ u + b4 (N=64, no relu, f32 out to Dl)
    {
        const int ntb4 = (w & 1) * 2;
        f32x4 acc[2];
        #pragma unroll
        for (int q = 0; q < 2; ++q) {
            const int n = (ntb4 + q) * 16 + rl;
            const float bv = (n < 50) ? b4[n] : 0.f;
            f32x4 av; av.x = bv; av.y = bv; av.z = bv; av.w = bv;
            acc[q] = av;
        }
        bf16x8 bfr[8];
        #pragma unroll
        for (int ks = 0; ks < 4; ++ks) {
            #pragma unroll
            for (int q = 0; q < 2; ++q)
                bfr[ks * 2 + q] = ldB(pack + PK4, 4, ntb4 + q, ks, lane);
        }
        #pragma unroll
        for (int ks = 0; ks < 4; ++ks) {
            const bf16x8 a = ldA(Vq, 128, mt * 16 + rl, ks * 32 + g8);
            #pragma unroll
            for (int q = 0; q < 2; ++q) acc[q] = MF(a, bfr[ks * 2 + q], acc[q]);
        }
        #pragma unroll
        for (int q = 0; q < 2; ++q) {
            const int n = (ntb4 + q) * 16 + rl;
            #pragma unroll
            for (int r = 0; r < 4; ++r) {
                const int tl = mt * 16 + dr + r;
                Dl[tl * 64 + (n ^ (tl & 31))] = acc[q][r];
            }
        }
    }
    __syncthreads();

    // delta -> global [n][t] (coalesced) + per-chunk sums
    for (int i = tid; i < 3200; i += 512) {
        const int n = i >> 6, l = i & 63;    // l == lane, n wave-uniform
        float v = Dl[l * 64 + (n ^ (l & 31))];
        if (t0 + l >= NS) v = 0.f;
        deltaT[n * NSP + t0 + l] = v;
        float s = v;
        #pragma unroll
        for (int off = 32; off > 0; off >>= 1) s += __shfl_xor(s, off, 64);
        if (l == 0) csum[n * NBLK + blk] = s;
    }
}

// ---------- k3: coff + h-scan + L5/Lz/Lt + losses ----------
__global__ __launch_bounds__(512)
void k3_predict(const float* __restrict__ z_seq, const float* __restrict__ term_seq,
                const float* __restrict__ b5, const float* __restrict__ bz,
                const float* __restrict__ Wt, const float* __restrict__ bt,
                float* __restrict__ ws)
{
    __shared__ unsigned short Hb[64 * 64];    // h rows bf16 (K 0..63)
    __shared__ unsigned short Ib[64 * 128];   // inter rows bf16 (K 64..191)
    __shared__ float Ub[64 * 64];             // delta staging; aliased as i5 after scan
    __shared__ unsigned short ZN[64 * 128];   // z_next rows bf16
    __shared__ float coff[56];
    __shared__ float red[8];
    unsigned short* i5 = (unsigned short*)Ub;

    const int tid  = threadIdx.x;
    const int lane = tid & 63;
    const int w    = __builtin_amdgcn_readfirstlane(tid >> 6);
    const int blk  = blockIdx.x;
    const int t0   = blk * 64;

    const unsigned short* pack = (const unsigned short*)(ws + OFF_PACK);
    const unsigned int* interR = (const unsigned int*)(ws + OFF_INTR);
    const float* deltaT = ws + OFF_DELT;
    const float* csum   = ws + OFF_CSUM;
    float* g_bz = ws + OFF_BZ;
    float* g_bt = ws + OFF_BT;

    // stage inter rows
    for (int i = tid; i < 4096; i += 512) {
        const int t = i >> 6, c2 = i & 63;
        *(unsigned int*)&Ib[((t << 7) + (c2 << 1)) ^ ((t & 7) << 3)] =
            interR[(size_t)(t0 + t) * 64 + c2];
    }
    // stage delta [t][n] f32 (lane-scan layout)
    for (int i = tid; i < 3200; i += 512) {
        const int n = i >> 6, l = i & 63;
        Ub[l * 64 + (n ^ (l & 31))] = deltaT[n * NSP + t0 + l];
    }
    // zero H pad cols 50..63
    for (int i = tid; i < 448; i += 512) {
        const int t = i / 7, p = i - t * 7;
        *(unsigned int*)&Hb[((t << 6) + 50 + 2 * p) ^ ((t & 7) << 3)] = 0u;
    }
    // stage z_next rows bf16
    for (int i = tid; i < 3200; i += 512) {
        const int t = i / 50, p = i - t * 50;
        int t1 = t0 + t + 1; t1 = t1 > NS ? NS : t1;
        const float2 z2 = *(const float2*)(z_seq + (size_t)t1 * 100 + 2 * p);
        *(unsigned int*)&ZN[((t << 7) + 2 * p) ^ ((t & 7) << 3)] =
            (unsigned int)f2bf(z2.x) | ((unsigned int)f2bf(z2.y) << 16);
    }
    // chunk offsets
    for (int n = w; n < 50; n += 8) {
        float s = 0.f;
        #pragma unroll
        for (int i2 = 0; i2 < 4; ++i2) {
            const int c = lane + (i2 << 6);
            if (c < blk) s += csum[n * NBLK + c];
        }
        #pragma unroll
        for (int off = 32; off > 0; off >>= 1) s += __shfl_xor(s, off, 64);
        if (lane == 0) coff[n] = s;
    }
    __syncthreads();

    // inclusive lane-scan per h-dim -> H bf16 rows
    for (int n = w; n < 50; n += 8) {
        float v = Ub[lane * 64 + (n ^ (lane & 31))];
        #pragma unroll
        for (int off = 1; off < 64; off <<= 1) {
            const float u = __shfl_up(v, off, 64);
            if (lane >= off) v += u;
        }
        const float h = v + coff[n];
        Hb[((lane << 6) + n) ^ ((lane & 7) << 3)] = f2bf(h);
    }
    __syncthreads();

    const int mt  = w >> 1;
    const int ntb = (w & 1) * 4;
    const int rl  = lane & 15;
    const int g8  = (lane >> 4) << 3;
    const int dr  = (lane >> 4) << 2;

    // L5: i5 = lrelu(W5 @ [h; inter] + b5), K = 192 (2 ksteps from H, 4 from I)
    {
        f32x4 acc[4];
        #pragma unroll
        for (int q = 0; q < 4; ++q) {
            const int n = (ntb + q) * 16 + rl;
            const float bv = (n < 100) ? b5[n] : 0.f;
            f32x4 av; av.x = bv; av.y = bv; av.z = bv; av.w = bv;
            acc[q] = av;
        }
        bf16x8 bfr[24];
        #pragma unroll
        for (int ks = 0; ks < 6; ++ks) {
            #pragma unroll
            for (int q = 0; q < 4; ++q)
                bfr[ks * 4 + q] = ldB(pack + PK5, 6, ntb + q, ks, lane);
        }
        #pragma unroll
        for (int ks = 0; ks < 6; ++ks) {
            const bf16x8 a = (ks < 2) ? ldA(Hb, 64, mt * 16 + rl, ks * 32 + g8)
                                      : ldA(Ib, 128, mt * 16 + rl, (ks - 2) * 32 + g8);
            #pragma unroll
            for (int q = 0; q < 4; ++q) acc[q] = MF(a, bfr[ks * 4 + q], acc[q]);
        }
        #pragma unroll
        for (int q = 0; q < 4; ++q) {
            const int col = (ntb + q) * 16 + rl;
            #pragma unroll
            for (int r = 0; r < 4; ++r) {
                const int row = mt * 16 + dr + r;
                const float v = lrelu(acc[q][r]);
                i5[((row << 7) + col) ^ ((row & 7) << 3)] = f2bf(v);
            }
        }
    }
    __syncthreads();

    // Lz: z_pred tiles + squared error vs ZN
    float zpart = 0.f;
    {
        f32x4 acc[4];
        #pragma unroll
        for (int q = 0; q < 4; ++q) {
            const int n = (ntb + q) * 16 + rl;
            const float bv = (n < 100) ? bz[n] : 0.f;
            f32x4 av; av.x = bv; av.y = bv; av.z = bv; av.w = bv;
            acc[q] = av;
        }
        bf16x8 bfr[16];
        #pragma unroll
        for (int ks = 0; ks < 4; ++ks) {
            #pragma unroll
            for (int q = 0; q < 4; ++q)
                bfr[ks * 4 + q] = ldB(pack + PKZ, 4, ntb + q, ks, lane);
        }
        #pragma unroll
        for (int ks = 0; ks < 4; ++ks) {
            const bf16x8 a = ldA(i5, 128, mt * 16 + rl, ks * 32 + g8);
            #pragma unroll
            for (int q = 0; q < 4; ++q) acc[q] = MF(a, bfr[ks * 4 + q], acc[q]);
        }
        #pragma unroll
        for (int q = 0; q < 4; ++q) {
            const int col = (ntb + q) * 16 + rl;
            if (col < 100) {
                #pragma unroll
                for (int r = 0; r < 4; ++r) {
                    const int row = mt * 16 + dr + r;
                    if (t0 + row < NS) {
                        const float zn = bf2f(ZN[((row << 7) + col) ^ ((row & 7) << 3)]);
                        const float d = zn - acc[q][r];
                        zpart += d * d;
                    }
                }
            }
        }
    }

    // Lt: t_logit + BCE (wave 0, lane = t)
    float tpart = 0.f;
    if (w == 0) {
        const bool vl = (t0 + lane) < NS;
        float a = bt[0];
        #pragma unroll
        for (int g = 0; g < 13; ++g) {
            const bf16x8 v = *(const bf16x8*)(i5 + ((((lane) << 7) + 8 * g) ^ ((lane & 7) << 3)));
            #pragma unroll
            for (int j = 0; j < 8; ++j) {
                const int c = 8 * g + j;
                if (c < 100) a = fmaf(bf2f((unsigned short)v[j]), Wt[c], a);
            }
        }
        if (vl) {
            const float y = term_seq[t0 + lane + 1];
            tpart = fmaxf(a, 0.f) - a * y + log1pf(expf(-fabsf(a)));
        }
    }

    #pragma unroll
    for (int off = 32; off > 0; off >>= 1) zpart += __shfl_xor(zpart, off, 64);
    if (lane == 0) red[w] = zpart;
    __syncthreads();
    if (tid == 0) {
        float s = 0.f;
        #pragma unroll
        for (int i = 0; i < 8; ++i) s += red[i];
        g_bz[blk] = s;
    }
    if (w == 0) {
        #pragma unroll
        for (int off = 32; off > 0; off >>= 1) tpart += __shfl_xor(tpart, off, 64);
        if (lane == 0) g_bt[blk] = tpart;
    }
}

// ---------- k4: final reduce ----------
__global__ __launch_bounds__(256)
void k4_final(const float* __restrict__ ws, float* __restrict__ out)
{
    __shared__ float rz[4], rt[4];
    const float* g_bz = ws + OFF_BZ;
    const float* g_bt = ws + OFF_BT;
    const int tid  = threadIdx.x;
    const int lane = tid & 63;
    const int w    = tid >> 6;
    float z = g_bz[tid];
    float t = g_bt[tid];
    #pragma unroll
    for (int off = 32; off > 0; off >>= 1) {
        z += __shfl_xor(z, off, 64);
        t += __shfl_xor(t, off, 64);
    }
    if (lane == 0) { rz[w] = z; rt[w] = t; }
    __syncthreads();
    if (tid == 0) {
        const float sz = rz[0] + rz[1] + rz[2] + rz[3];
        const float st = rt[0] + rt[1] + rt[2] + rt[3];
        const float zl = sz / (100.0f * NS);
        const float tl = st / NS;
        out[0] = zl + tl;
        out[1] = zl;
        out[2] = tl;
    }
}

extern "C" void kernel_launch(void* const* d_in, const int* in_sizes, int n_in,
                              void* d_out, int out_size, void* d_ws, size_t ws_size,
                              hipStream_t stream)
{
    const float* z_seq = (const float*)d_in[0];
    const float* a_seq = (const float*)d_in[1];
    const float* term  = (const float*)d_in[2];
    const float* W1 = (const float*)d_in[3];  const float* b1 = (const float*)d_in[4];
    const float* W2 = (const float*)d_in[5];  const float* b2 = (const float*)d_in[6];
    const float* W3 = (const float*)d_in[7];  const float* b3 = (const float*)d_in[8];
    const float* W4 = (const float*)d_in[9];  const float* b4 = (const float*)d_in[10];
    const float* W5 = (const float*)d_in[11]; const float* b5 = (const float*)d_in[12];
    const float* Wz = (const float*)d_in[13]; const float* bz = (const float*)d_in[14];
    const float* Wt = (const float*)d_in[15]; const float* bt = (const float*)d_in[16];
    float* out = (float*)d_out;
    float* ws  = (float*)d_ws;

    k0_pack<<<384, 256, 0, stream>>>(W1, W2, W3, W4, W5, Wz, ws);
    k1_encode<<<NBLK, 512, 0, stream>>>(z_seq, a_seq, b1, b2, b3, b4, ws);
    k3_predict<<<NBLK, 512, 0, stream>>>(z_seq, term, b5, bz, Wt, bt, ws);
    k4_final<<<1, 256, 0, stream>>>(ws, out);
}